// Round 6
// baseline (263.394 us; speedup 1.0000x reference)
//
#include <hip/hip_runtime.h>

// Problem constants: N=B*T=65536, D=256, K=1024
#define NTOT 65536
#define DDIM 256
#define KCB  1024
#define ND   16777216   // NTOT * DDIM

typedef __attribute__((ext_vector_type(4))) float f32x4;
typedef __attribute__((ext_vector_type(4))) int   i32x4;
typedef __attribute__((ext_vector_type(8))) int   i32x8;
typedef __attribute__((ext_vector_type(4))) unsigned u32x4;

__device__ static inline unsigned umax32(unsigned a, unsigned b) { return a > b ? a : b; }

// ---- fp32 -> fp8 e4m3fn (OCP), 4-at-a-time pack into an int (byte i = x_i) --
#if !__has_builtin(__builtin_amdgcn_cvt_pk_fp8_f32)
__device__ static inline unsigned f32_to_e4m3_1(float f) {
    unsigned u = __float_as_uint(f);
    unsigned s = (u >> 24) & 0x80u;
    unsigned a = u & 0x7fffffffu;
    float x = __uint_as_float(a);
    if (x >= 448.f) return s | 0x7Eu;
    if (x < 0.015625f) {                    // subnormal: multiples of 2^-9
        int m = (int)__builtin_rintf(x * 512.f);   // RNE, 0..8
        return s | (unsigned)m;             // m==8 -> 0x08 == 2^-6 normal, correct
    }
    unsigned r = (a + 0x7FFFFu + ((a >> 20) & 1u)) >> 20;   // RNE to 3 mantissa bits
    int E = (int)(r >> 3) - 127;
    unsigned code = ((unsigned)(E + 7) << 3) | (r & 7u);
    if (code >= 0x7Fu) code = 0x7Eu;
    return s | code;
}
#endif

__device__ static inline int pk4_fp8(float x0, float x1, float x2, float x3) {
#if __has_builtin(__builtin_amdgcn_cvt_pk_fp8_f32)
    int w = __builtin_amdgcn_cvt_pk_fp8_f32(x0, x1, 0, false);   // bytes 0,1
    w = __builtin_amdgcn_cvt_pk_fp8_f32(x2, x3, w, true);        // bytes 2,3
    return w;
#else
    return (int)(f32_to_e4m3_1(x0) | (f32_to_e4m3_1(x1) << 8) |
                 (f32_to_e4m3_1(x2) << 16) | (f32_to_e4m3_1(x3) << 24));
#endif
}

// ---------------- Prep: codebook -> fp8(x512) MX-fragments + 256*||e||^2 -----
// Fragment layout for mfma_scale_f32_16x16x128_f8f6f4: lane l of a B-frag
// holds col = l&15, k = kf*128 + (l>>4)*32 + j (j=0..31), as two 16-B granules
// h (bytes j<16 / j>=16). Byte addr:
//   ((cc*2 + kf)*2 + h)*1024 + ((q)*16 + (c&15))*16 + (k&15)
// where cc = c>>4 (16-col chunk), q = (k>>5)&3.
__global__ __launch_bounds__(256) void vq_prep_kernel(const float* __restrict__ cb,
                                                      char* __restrict__ cbf,
                                                      float* __restrict__ esq_scaled,
                                                      float* __restrict__ loss_out) {
    int gid = blockIdx.x * 256 + threadIdx.x;   // 0..32767
    int c = gid >> 5;
    int j8 = gid & 31;                          // owns k = j8*8 .. j8*8+7
    const float* p = cb + (size_t)c * DDIM + j8 * 8;
    f32x4 x = *(const f32x4*)p;
    f32x4 y = *(const f32x4*)(p + 4);
    float ss = x[0]*x[0] + x[1]*x[1] + x[2]*x[2] + x[3]*x[3]
             + y[0]*y[0] + y[1]*y[1] + y[2]*y[2] + y[3]*y[3];
    #pragma unroll
    for (int m = 16; m; m >>= 1) ss += __shfl_xor(ss, m);   // reduce the 32 lanes of code c
    if (j8 == 0) esq_scaled[c] = 256.f * ss;                // 512 * 0.5 * ||e||^2
    int w0 = pk4_fp8(512.f * x[0], 512.f * x[1], 512.f * x[2], 512.f * x[3]);
    int w1 = pk4_fp8(512.f * y[0], 512.f * y[1], 512.f * y[2], 512.f * y[3]);
    // k = j8*8: kf = j8>>4, q = (j8>>2)&3, h = (j8>>1)&1, byte = (j8&1)*8
    int cc = c >> 4, kf = j8 >> 4, q = (j8 >> 2) & 3, h = (j8 >> 1) & 1;
    size_t addr = (size_t)(((cc * 2 + kf) * 2 + h) * 1024)
                + (size_t)(q * 16 + (c & 15)) * 16 + (j8 & 1) * 8;
    *(long long*)(cbf + addr) = (long long)(unsigned)w0 | ((long long)w1 << 32);
    if (gid == 0) loss_out[0] = 0.f;
}

// ---------------- Main: r5 structure + full residency + 2-deep B prefetch ----
// 1024 blocks x 256 thr (4 waves, wave cg owns 64 rows x 256 cols).
// Changes vs r5 (which measured 49us, MfmaUtil 12.5% => K-loop off critical
// path, stall-bound): (1) __launch_bounds__(256,4) -- the grid needs 4
// blocks/CU co-resident; all prior rounds ran at ~launch_bounds residency
// (occupancy tracked the 2nd arg, never the VGPR/LDS ceiling). (2) B prefetch
// distance-2 with the same 2 buffers: copy Bc->bv, issue chunk-(c+2) loads
// into the freed buffer, then MFMA -- each buffer is in flight ~2 chunk
// periods before its wait, covering loaded-L2 latency.
__global__ __launch_bounds__(256, 4) void vq_main_kernel(const float* __restrict__ z,
                                                         const float* __restrict__ cb,
                                                         const char* __restrict__ cbf,
                                                         const float* __restrict__ esq_scaled,
                                                         float* __restrict__ out) {
    __shared__ i32x4 A4[1024];          // 16 KB: granule ((rf*2+kf)*2+h)*64 + lane
    __shared__ float esq_s[KCB];        // 4 KB: 64 - 256*||e||^2
    __shared__ float zsq_s[64];
    __shared__ unsigned ur_s[256];      // [cg][row] packed keys
    __shared__ int idx_s[64];

    const int tid  = threadIdx.x;
    const int cg   = tid >> 6;          // wave id = column group (cols cg*256..)
    const int lane = tid & 63;
    const int q    = lane >> 4;
    const int ln   = lane & 15;
    // pack mapping: thread (r, t) owns row r, cols t*64..t*64+63
    const int r = tid >> 2, t = tid & 3;
    const int mm = r & 15;
    const int rf_own = r >> 4;
    const int b0 = blockIdx.x * 64;

    #pragma unroll
    for (int i = 0; i < 4; ++i) {
        int ix = tid + i * 256;
        esq_s[ix] = 64.0f - esq_scaled[ix];   // bias +64 folded in, negated
    }

    // early B prefetch: chunks 0 and 1 (L2-resident after first touch)
    // chunk byte stride within cg region: 4096 (2 kf x 2 h x 1024)
    const char* bbase = cbf + (size_t)cg * 65536 + lane * 16;
    i32x4 B0[4], B1[4];                 // [kf*2 + h]
    #pragma unroll
    for (int j = 0; j < 4; ++j) {
        B0[j] = *(const i32x4*)(bbase + j * 1024);
        B1[j] = *(const i32x4*)(bbase + 4096 + j * 1024);
    }

    // ---- cooperative A load/pack: thread (r, t) owns 64 floats -------------
    {
        const float* zp = z + (size_t)(b0 + r) * DDIM + t * 64;
        f32x4 v[16];
        #pragma unroll
        for (int i = 0; i < 16; ++i) v[i] = *(const f32x4*)(zp + i * 4);
        float sq = 0.f;
        #pragma unroll
        for (int s = 0; s < 2; ++s) {           // k-32-block kb = 2t+s
            const int kb = 2 * t + s;
            const int kf = kb >> 2, qq = kb & 3;
            int w[8];
            #pragma unroll
            for (int j = 0; j < 8; ++j) {
                f32x4 x = v[s * 8 + j];
                sq += x[0]*x[0] + x[1]*x[1] + x[2]*x[2] + x[3]*x[3];
                w[j] = pk4_fp8(x[0], x[1], x[2], x[3]);
            }
            const int g = ((rf_own * 2 + kf) * 2) * 64 + qq * 16 + mm;
            A4[g]      = (i32x4){w[0], w[1], w[2], w[3]};   // h=0
            A4[g + 64] = (i32x4){w[4], w[5], w[6], w[7]};   // h=1
        }
        sq += __shfl_xor(sq, 1);
        sq += __shfl_xor(sq, 2);               // row sum over the 4 t-lanes
        if (t == 0) zsq_s[r] = sq;
    }
    __syncthreads();

    // ---- A frags to regs: lane-contiguous ds_read_b128 (conflict-free) ----
    i32x8 av[4][2];
    #pragma unroll
    for (int rf = 0; rf < 4; ++rf)
        #pragma unroll
        for (int kf = 0; kf < 2; ++kf) {
            i32x4* ph = (i32x4*)&av[rf][kf];
            ph[0] = A4[((rf * 2 + kf) * 2 + 0) * 64 + lane];
            ph[1] = A4[((rf * 2 + kf) * 2 + 1) * 64 + lane];
        }

    unsigned best[16];
    #pragma unroll
    for (int i = 0; i < 16; ++i) best[i] = 0u;
    const float* ep = esq_s + cg * 256 + ln;
    const int colinv0 = 1023 - cg * 256 - ln;

    // ---- K-loop: 16 chunks of 16 cols, distance-2 prefetch, no barriers ----
    // Step c: bv <- Bb (copy), Bb <- loads for chunk (c+2), MFMA(bv), keys.
#define VQ_STEP(Bb_, C_)                                                       \
    {                                                                          \
        i32x8 bv0, bv1;                                                        \
        ((i32x4*)&bv0)[0] = Bb_[0]; ((i32x4*)&bv0)[1] = Bb_[1];                \
        ((i32x4*)&bv1)[0] = Bb_[2]; ((i32x4*)&bv1)[1] = Bb_[3];                \
        _Pragma("unroll")                                                      \
        for (int j = 0; j < 4; ++j)                                            \
            Bb_[j] = *(const i32x4*)(bbase + (size_t)(((C_) + 2) & 15) * 4096 + j * 1024); \
        const float e4 = ep[(C_) * 16];                                        \
        f32x4 ac0 = {e4, e4, e4, e4};                                          \
        f32x4 ac1 = ac0, ac2 = ac0, ac3 = ac0;                                 \
        __builtin_amdgcn_s_setprio(1);                                         \
        ac0 = __builtin_amdgcn_mfma_scale_f32_16x16x128_f8f6f4(av[0][0], bv0, ac0, 0, 0, 0, 0x7F7F7F7F, 0, 0x7F7F7F7F); \
        ac1 = __builtin_amdgcn_mfma_scale_f32_16x16x128_f8f6f4(av[1][0], bv0, ac1, 0, 0, 0, 0x7F7F7F7F, 0, 0x7F7F7F7F); \
        ac2 = __builtin_amdgcn_mfma_scale_f32_16x16x128_f8f6f4(av[2][0], bv0, ac2, 0, 0, 0, 0x7F7F7F7F, 0, 0x7F7F7F7F); \
        ac3 = __builtin_amdgcn_mfma_scale_f32_16x16x128_f8f6f4(av[3][0], bv0, ac3, 0, 0, 0, 0x7F7F7F7F, 0, 0x7F7F7F7F); \
        ac0 = __builtin_amdgcn_mfma_scale_f32_16x16x128_f8f6f4(av[0][1], bv1, ac0, 0, 0, 0, 0x7F7F7F7F, 0, 0x7F7F7F7F); \
        ac1 = __builtin_amdgcn_mfma_scale_f32_16x16x128_f8f6f4(av[1][1], bv1, ac1, 0, 0, 0, 0x7F7F7F7F, 0, 0x7F7F7F7F); \
        ac2 = __builtin_amdgcn_mfma_scale_f32_16x16x128_f8f6f4(av[2][1], bv1, ac2, 0, 0, 0, 0x7F7F7F7F, 0, 0x7F7F7F7F); \
        ac3 = __builtin_amdgcn_mfma_scale_f32_16x16x128_f8f6f4(av[3][1], bv1, ac3, 0, 0, 0, 0x7F7F7F7F, 0, 0x7F7F7F7F); \
        __builtin_amdgcn_s_setprio(0);                                         \
        const unsigned ci = (unsigned)(colinv0 - (C_) * 16);                   \
        _Pragma("unroll")                                                      \
        for (int i = 0; i < 4; ++i) {                                          \
            best[i]      = umax32(best[i],      (__float_as_uint(ac0[i]) & 0xFFFFFC00u) | ci); \
            best[4 + i]  = umax32(best[4 + i],  (__float_as_uint(ac1[i]) & 0xFFFFFC00u) | ci); \
            best[8 + i]  = umax32(best[8 + i],  (__float_as_uint(ac2[i]) & 0xFFFFFC00u) | ci); \
            best[12 + i] = umax32(best[12 + i], (__float_as_uint(ac3[i]) & 0xFFFFFC00u) | ci); \
        }                                                                      \
    }

    for (int c = 0; c < 16; c += 2) {
        VQ_STEP(B0, c);
        VQ_STEP(B1, c + 1);     // wrap loads re-read chunks 0/1: harmless
    }
#undef VQ_STEP

    // ---- reduce over the 16 ln-lanes of each q-group (integer max only) ----
    #pragma unroll
    for (int m = 1; m < 16; m <<= 1)
        #pragma unroll
        for (int i = 0; i < 16; ++i)
            best[i] = umax32(best[i], (unsigned)__shfl_xor((int)best[i], m));

    if (ln == 0) {
        #pragma unroll
        for (int rf = 0; rf < 4; ++rf) {
            u32x4 v = {best[rf * 4 + 0], best[rf * 4 + 1],
                       best[rf * 4 + 2], best[rf * 4 + 3]};
            *(u32x4*)(ur_s + cg * 64 + rf * 16 + q * 4) = v;   // rows rf*16+q*4+i
        }
    }
    __syncthreads();

    if (tid < 64) {
        unsigned u = umax32(umax32(ur_s[tid], ur_s[64 + tid]),
                            umax32(ur_s[128 + tid], ur_s[192 + tid]));
        int k = 1023 - (int)(u & 1023u);
        // midpoint-reconstruct the truncated score: s+64
        float sval = __uint_as_float((u & 0xFFFFFC00u) | 0x200u) - 64.0f;
        idx_s[tid] = k;
        // row loss: ||z-e*||^2 = ||z||^2 - s/256
        float lsum = zsq_s[tid] - sval * 0.00390625f;
        #pragma unroll
        for (int off = 32; off; off >>= 1) lsum += __shfl_down(lsum, off);
        if (tid == 0) atomicAdd(out + ND, lsum * (1.0f / (float)ND));
    }
    __syncthreads();

    // ---- epilogue: float4 gather + non-temporal store ----------------------
    #pragma unroll
    for (int i = 0; i < 16; ++i) {
        int item = tid + i * 256;
        int row = item >> 6, c4 = item & 63;
        int k = idx_s[row];
        f32x4 v = *(const f32x4*)(cb + (size_t)k * DDIM + c4 * 4);
        __builtin_nontemporal_store(v, (f32x4*)(out + (size_t)(b0 + row) * DDIM + c4 * 4));
    }
}

extern "C" void kernel_launch(void* const* d_in, const int* in_sizes, int n_in,
                              void* d_out, int out_size, void* d_ws, size_t ws_size,
                              hipStream_t stream) {
    const float* z  = (const float*)d_in[0];   // z_e, 65536 x 256 fp32
    const float* cb = (const float*)d_in[1];   // codebook, 1024 x 256 fp32
    float* out = (float*)d_out;                // z_q (16777216) ++ loss (1)

    float* esq_scaled = (float*)d_ws;                    // 4 KB
    char*  cb_frag    = (char*)d_ws + 4096;              // 256 KB fp8 MX fragments

    vq_prep_kernel<<<128, 256, 0, stream>>>(cb, cb_frag, esq_scaled, out + ND);
    vq_main_kernel<<<NTOT / 64, 256, 0, stream>>>(z, cb, cb_frag, esq_scaled, out);
}

// Round 7
// 146.352 us; speedup vs baseline: 1.7997x; 1.7997x over previous
//
#include <hip/hip_runtime.h>

// Problem constants: N=B*T=65536, D=256, K=1024
#define NTOT 65536
#define DDIM 256
#define KCB  1024
#define ND   16777216   // NTOT * DDIM

typedef __attribute__((ext_vector_type(4))) float f32x4;
typedef __attribute__((ext_vector_type(4))) int   i32x4;
typedef __attribute__((ext_vector_type(8))) int   i32x8;

__device__ static inline unsigned umax32(unsigned a, unsigned b) { return a > b ? a : b; }

// ---- fp32 -> fp8 e4m3fn (OCP), 4-at-a-time pack into an int (byte i = x_i) --
#if !__has_builtin(__builtin_amdgcn_cvt_pk_fp8_f32)
__device__ static inline unsigned f32_to_e4m3_1(float f) {
    unsigned u = __float_as_uint(f);
    unsigned s = (u >> 24) & 0x80u;
    unsigned a = u & 0x7fffffffu;
    float x = __uint_as_float(a);
    if (x >= 448.f) return s | 0x7Eu;
    if (x < 0.015625f) {                    // subnormal: multiples of 2^-9
        int m = (int)__builtin_rintf(x * 512.f);   // RNE, 0..8
        return s | (unsigned)m;             // m==8 -> 0x08 == 2^-6 normal, correct
    }
    unsigned r = (a + 0x7FFFFu + ((a >> 20) & 1u)) >> 20;   // RNE to 3 mantissa bits
    int E = (int)(r >> 3) - 127;
    unsigned code = ((unsigned)(E + 7) << 3) | (r & 7u);
    if (code >= 0x7Fu) code = 0x7Eu;
    return s | code;
}
#endif

__device__ static inline int pk4_fp8(float x0, float x1, float x2, float x3) {
#if __has_builtin(__builtin_amdgcn_cvt_pk_fp8_f32)
    int w = __builtin_amdgcn_cvt_pk_fp8_f32(x0, x1, 0, false);   // bytes 0,1
    w = __builtin_amdgcn_cvt_pk_fp8_f32(x2, x3, w, true);        // bytes 2,3
    return w;
#else
    return (int)(f32_to_e4m3_1(x0) | (f32_to_e4m3_1(x1) << 8) |
                 (f32_to_e4m3_1(x2) << 16) | (f32_to_e4m3_1(x3) << 24));
#endif
}

// ---------------- Prep: codebook -> fp8(x512) MX-fragments + biased esq ------
// Fragment layout for mfma_scale_f32_16x16x128_f8f6f4 (same as r5, verified):
// lane l of a B-frag holds col = l&15, k = kf*128 + (l>>4)*32 + j (j=0..31),
// as two 16-B granules h. Byte addr:
//   ((cc*2 + kf)*2 + h)*1024 + ((q)*16 + (c&15))*16 + (k&15)
// esq stores 64 - 256*||e||^2 (pre-biased C-init for the main kernel).
__global__ __launch_bounds__(256) void vq_prep_kernel(const float* __restrict__ cb,
                                                      char* __restrict__ cbf,
                                                      float* __restrict__ esq_scaled,
                                                      float* __restrict__ loss_out) {
    int gid = blockIdx.x * 256 + threadIdx.x;   // 0..32767
    int c = gid >> 5;
    int j8 = gid & 31;                          // owns k = j8*8 .. j8*8+7
    const float* p = cb + (size_t)c * DDIM + j8 * 8;
    f32x4 x = *(const f32x4*)p;
    f32x4 y = *(const f32x4*)(p + 4);
    float ss = x[0]*x[0] + x[1]*x[1] + x[2]*x[2] + x[3]*x[3]
             + y[0]*y[0] + y[1]*y[1] + y[2]*y[2] + y[3]*y[3];
    #pragma unroll
    for (int m = 16; m; m >>= 1) ss += __shfl_xor(ss, m);   // reduce the 32 lanes of code c
    if (j8 == 0) esq_scaled[c] = 64.0f - 256.f * ss;        // pre-biased, pre-negated
    int w0 = pk4_fp8(512.f * x[0], 512.f * x[1], 512.f * x[2], 512.f * x[3]);
    int w1 = pk4_fp8(512.f * y[0], 512.f * y[1], 512.f * y[2], 512.f * y[3]);
    // k = j8*8: kf = j8>>4, q = (j8>>2)&3, h = (j8>>1)&1, byte = (j8&1)*8
    int cc = c >> 4, kf = j8 >> 4, q = (j8 >> 2) & 3, h = (j8 >> 1) & 1;
    size_t addr = (size_t)(((cc * 2 + kf) * 2 + h) * 1024)
                + (size_t)(q * 16 + (c & 15)) * 16 + (j8 & 1) * 8;
    *(long long*)(cbf + addr) = (long long)(unsigned)w0 | ((long long)w1 << 32);
    if (gid == 0) loss_out[0] = 0.f;
}

// ---------------- Main: 1024 independent waves, zero LDS, zero barriers ------
// 256 blocks x 256 thr = 1 block/CU, 1 wave/SIMD, ALL resident at t=0 (no
// tail, no lockstep). Each wave owns 64 rows x all 1024 cols:
//  - A-frags per-lane direct from global (16B chunks hit the same 64B sectors
//    as a coalesced load -- no penalty), packed in-register. No LDS, no barrier.
//  - in-wave shfl argmin (wave spans all cols), loss + gather from registers.
//  - ILP covers latency: 64 z-loads in flight/lane, distance-2 B ping-pong
//    from the L2-resident 256KB cbf, 64 independent gathers+NT stores.
// Argmin via packed keys: acc init = 64-256||e||^2 => final acc = s+64 > 0;
// key = (as_uint & ~1023) | (1023-col); exact lowest-index tie-break.
__global__ __launch_bounds__(256, 1) void vq_main_kernel(const float* __restrict__ z,
                                                         const float* __restrict__ cb,
                                                         const char* __restrict__ cbf,
                                                         const float* __restrict__ esq_scaled,
                                                         float* __restrict__ out) {
    const int tid  = threadIdx.x;
    const int lane = tid & 63;
    const int wv   = tid >> 6;
    const int q    = lane >> 4;
    const int ln   = lane & 15;
    const int base = (blockIdx.x * 4 + wv) * 64;   // this wave's 64 rows

    // B chunks 0,1 prefetch (L2-resident after first touch); esq chunks 0,1
    const char* bbase = cbf + (size_t)lane * 16;
    i32x4 B0[4], B1[4];                 // [kf*2 + h]
    #pragma unroll
    for (int j = 0; j < 4; ++j) {
        B0[j] = *(const i32x4*)(bbase + j * 1024);
        B1[j] = *(const i32x4*)(bbase + 4096 + j * 1024);
    }
    float e_cur = esq_scaled[ln];
    float e_nxt = esq_scaled[16 + ln];

    // ---- A: per-lane direct load + in-register fp8 pack + row ||z||^2 ------
    // lane(q,ln) holds rows rf*16+ln, k = kf*128 + q*32 + j (j=0..31).
    i32x8 av[4][2];
    float zsq[4];
    #pragma unroll
    for (int rf = 0; rf < 4; ++rf) {
        float sq = 0.f;
        #pragma unroll
        for (int kf = 0; kf < 2; ++kf) {
            const float* ap = z + (size_t)(base + rf * 16 + ln) * DDIM + kf * 128 + q * 32;
            int wrd[8];
            #pragma unroll
            for (int j = 0; j < 8; ++j) {
                f32x4 x = *(const f32x4*)(ap + j * 4);
                sq += x[0]*x[0] + x[1]*x[1] + x[2]*x[2] + x[3]*x[3];
                wrd[j] = pk4_fp8(x[0], x[1], x[2], x[3]);
            }
            i32x8 v;
            #pragma unroll
            for (int j = 0; j < 8; ++j) v[j] = wrd[j];
            av[rf][kf] = v;
        }
        sq += __shfl_xor(sq, 16);
        sq += __shfl_xor(sq, 32);       // sum the 4 q-slices: full row sum
        zsq[rf] = sq;
    }

    unsigned best[16];
    #pragma unroll
    for (int i = 0; i < 16; ++i) best[i] = 0u;
    const int colinv0 = 1023 - ln;

    // ---- K-loop: 64 chunks of 16 cols, distance-2 ping-pong, no barriers ---
#define VQ_STEP(Bb_, C_)                                                       \
    {                                                                          \
        i32x8 bv0, bv1;                                                        \
        ((i32x4*)&bv0)[0] = Bb_[0]; ((i32x4*)&bv0)[1] = Bb_[1];                \
        ((i32x4*)&bv1)[0] = Bb_[2]; ((i32x4*)&bv1)[1] = Bb_[3];                \
        _Pragma("unroll")                                                      \
        for (int j = 0; j < 4; ++j)                                            \
            Bb_[j] = *(const i32x4*)(bbase + (size_t)(((C_) + 2) & 63) * 4096 + j * 1024); \
        const float e4 = e_cur;                                                \
        e_cur = e_nxt;                                                         \
        e_nxt = esq_scaled[(((C_) + 2) & 63) * 16 + ln];                       \
        f32x4 ac0 = {e4, e4, e4, e4};                                          \
        f32x4 ac1 = ac0, ac2 = ac0, ac3 = ac0;                                 \
        __builtin_amdgcn_s_setprio(1);                                         \
        ac0 = __builtin_amdgcn_mfma_scale_f32_16x16x128_f8f6f4(av[0][0], bv0, ac0, 0, 0, 0, 0x7F7F7F7F, 0, 0x7F7F7F7F); \
        ac1 = __builtin_amdgcn_mfma_scale_f32_16x16x128_f8f6f4(av[1][0], bv0, ac1, 0, 0, 0, 0x7F7F7F7F, 0, 0x7F7F7F7F); \
        ac2 = __builtin_amdgcn_mfma_scale_f32_16x16x128_f8f6f4(av[2][0], bv0, ac2, 0, 0, 0, 0x7F7F7F7F, 0, 0x7F7F7F7F); \
        ac3 = __builtin_amdgcn_mfma_scale_f32_16x16x128_f8f6f4(av[3][0], bv0, ac3, 0, 0, 0, 0x7F7F7F7F, 0, 0x7F7F7F7F); \
        ac0 = __builtin_amdgcn_mfma_scale_f32_16x16x128_f8f6f4(av[0][1], bv1, ac0, 0, 0, 0, 0x7F7F7F7F, 0, 0x7F7F7F7F); \
        ac1 = __builtin_amdgcn_mfma_scale_f32_16x16x128_f8f6f4(av[1][1], bv1, ac1, 0, 0, 0, 0x7F7F7F7F, 0, 0x7F7F7F7F); \
        ac2 = __builtin_amdgcn_mfma_scale_f32_16x16x128_f8f6f4(av[2][1], bv1, ac2, 0, 0, 0, 0x7F7F7F7F, 0, 0x7F7F7F7F); \
        ac3 = __builtin_amdgcn_mfma_scale_f32_16x16x128_f8f6f4(av[3][1], bv1, ac3, 0, 0, 0, 0x7F7F7F7F, 0, 0x7F7F7F7F); \
        __builtin_amdgcn_s_setprio(0);                                         \
        const unsigned ci = (unsigned)(colinv0 - (C_) * 16);                   \
        _Pragma("unroll")                                                      \
        for (int i = 0; i < 4; ++i) {                                          \
            best[i]      = umax32(best[i],      (__float_as_uint(ac0[i]) & 0xFFFFFC00u) | ci); \
            best[4 + i]  = umax32(best[4 + i],  (__float_as_uint(ac1[i]) & 0xFFFFFC00u) | ci); \
            best[8 + i]  = umax32(best[8 + i],  (__float_as_uint(ac2[i]) & 0xFFFFFC00u) | ci); \
            best[12 + i] = umax32(best[12 + i], (__float_as_uint(ac3[i]) & 0xFFFFFC00u) | ci); \
        }                                                                      \
    }

    for (int c = 0; c < 64; c += 2) {
        VQ_STEP(B0, c);
        VQ_STEP(B1, c + 1);     // wrap loads re-read chunks 0/1: harmless
    }
#undef VQ_STEP

    // ---- in-wave argmin reduce over the 16 ln-lanes of each q-group --------
    // After this, every lane holds winners for rows base + rf*16 + q*4 + i.
    #pragma unroll
    for (int m = 1; m < 16; m <<= 1)
        #pragma unroll
        for (int i = 0; i < 16; ++i)
            best[i] = umax32(best[i], (unsigned)__shfl_xor((int)best[i], m));

    // ---- loss: lane (q, ln=q*4+i) holds zsq for exactly its winner rows ----
    float lcl = 0.f;
    if ((ln >> 2) == q) {
        const int i = ln & 3;
        #pragma unroll
        for (int rf = 0; rf < 4; ++rf) {
            unsigned u = best[rf * 4 + i];
            // midpoint-reconstruct the truncated score: s+64
            float sval = __uint_as_float((u & 0xFFFFFC00u) | 0x200u) - 64.0f;
            lcl += zsq[rf] - sval * 0.00390625f;   // ||z-e*||^2 = ||z||^2 - s/256
        }
    }
    #pragma unroll
    for (int off = 32; off; off >>= 1) lcl += __shfl_xor(lcl, off);
    if (lane == 0) atomicAdd(out + ND, lcl * (1.0f / (float)ND));

    // ---- epilogue: gather + NT store straight from registers ---------------
    // lane(q,ln): rows rf*16+q*4+i, cols ln*4 + j*64 (16 contiguous lanes =
    // 256B segments per instruction).
    #pragma unroll
    for (int rf = 0; rf < 4; ++rf)
        #pragma unroll
        for (int i = 0; i < 4; ++i) {
            const int row = base + rf * 16 + q * 4 + i;
            const int k = 1023 - (int)(best[rf * 4 + i] & 1023u);
            const float* src = cb + (size_t)k * DDIM + ln * 4;
            float* dst = out + (size_t)row * DDIM + ln * 4;
            #pragma unroll
            for (int j = 0; j < 4; ++j) {
                f32x4 v = *(const f32x4*)(src + j * 64);
                __builtin_nontemporal_store(v, (f32x4*)(dst + j * 64));
            }
        }
}

extern "C" void kernel_launch(void* const* d_in, const int* in_sizes, int n_in,
                              void* d_out, int out_size, void* d_ws, size_t ws_size,
                              hipStream_t stream) {
    const float* z  = (const float*)d_in[0];   // z_e, 65536 x 256 fp32
    const float* cb = (const float*)d_in[1];   // codebook, 1024 x 256 fp32
    float* out = (float*)d_out;                // z_q (16777216) ++ loss (1)

    float* esq_scaled = (float*)d_ws;                    // 4 KB
    char*  cb_frag    = (char*)d_ws + 4096;              // 256 KB fp8 MX fragments

    vq_prep_kernel<<<128, 256, 0, stream>>>(cb, cb_frag, esq_scaled, out + ND);
    vq_main_kernel<<<256, 256, 0, stream>>>(z, cb, cb_frag, esq_scaled, out);
}